// Round 7
// baseline (178.020 us; speedup 1.0000x reference)
//
#include <hip/hip_runtime.h>
#include <math.h>

#define HW     76800
#define HW4    19200
#define NCH    86
#define OCH    89
#define NB     4
#define VOX    32768
#define NBLKV  75         // f4 blocks per batch (1024 px each)
#define THRESHF 0.7f
#define BIGF   1e30f

typedef float f4 __attribute__((ext_vector_type(4)));

// ws float layout:
// [64..207]   M: (b*3 + k)*12 row-major 3x4 [R|t]     (written by k_minmax bx==0)
// [256..279]  minmax keys (uint32): b*6 + c           (init by k_votes_zero blk(0,0))
// [512..5312) vote partials: (b*75+bx)*16 + i, i<14   (k_votes_zero)
// [32768..]   occ_tmp: [b][vox][64] voxel-major scratch (33.5 MB)

__device__ __forceinline__ float sigmoidf_(float x) {
    if (x >= 0.f) { return 1.f / (1.f + expf(-x)); }
    float e = expf(x); return e / (1.f + e);
}
__device__ __forceinline__ unsigned fkey(float f) {
    unsigned u = __float_as_uint(f);
    return (u & 0x80000000u) ? ~u : (u | 0x80000000u);
}
__device__ __forceinline__ float funkey(unsigned k) {
    unsigned u = (k & 0x80000000u) ? (k ^ 0x80000000u) : ~k;
    return __uint_as_float(u);
}
__device__ __forceinline__ int vox1(float q) {
    int v = (int)floorf(q * 32.f);
    return v < 0 ? 0 : (v > 31 ? 31 : v);
}

// votes + zero occ_tmp + init minmax keys + copy ch {3..15,20,21}
__global__ __launch_bounds__(256) void k_votes_zero(const f4* __restrict__ in4,
                                                    f4* __restrict__ out4,
                                                    float* __restrict__ ws,
                                                    f4* __restrict__ zp, unsigned n4) {
    const int b = blockIdx.y, bx = blockIdx.x;
    const int tid = threadIdx.x;
    {   // zero slice of scratch
        unsigned gid = ((unsigned)(b * NBLKV + bx)) * 256u + tid;
        f4 z = {0.f, 0.f, 0.f, 0.f};
        for (unsigned i = gid; i < n4; i += NB * NBLKV * 256u)
            __builtin_nontemporal_store(z, &zp[i]);
    }
    if (b == 0 && bx == 0 && tid < 24) {
        unsigned* keys = (unsigned*)(ws + 256);
        keys[tid] = ((tid % 6) < 3) ? fkey(BIGF) : fkey(-BIGF);
    }
    const size_t ib = (size_t)b * NCH * HW4 + bx * 256 + tid;
    const size_t ob = (size_t)b * OCH * HW4 + bx * 256 + tid;
    f4 mv = in4[ib + (size_t)3 * HW4];
    f4 c0 = in4[ib + (size_t)20 * HW4];
    f4 c1 = in4[ib + (size_t)21 * HW4];
    f4 L[12];
#pragma unroll
    for (int i = 0; i < 12; i++) L[i] = in4[ib + (size_t)(4 + i) * HW4];
    // copy-out the channels this kernel already read
    __builtin_nontemporal_store(mv, &out4[ob + (size_t)3 * HW4]);
    __builtin_nontemporal_store(c0, &out4[ob + (size_t)20 * HW4]);
    __builtin_nontemporal_store(c1, &out4[ob + (size_t)21 * HW4]);
#pragma unroll
    for (int i = 0; i < 12; i++)
        __builtin_nontemporal_store(L[i], &out4[ob + (size_t)(4 + i) * HW4]);

    float acc[14];
#pragma unroll
    for (int i = 0; i < 14; i++) acc[i] = 0.f;
#pragma unroll
    for (int k = 0; k < 4; k++) {
        float m  = sigmoidf_(mv[k]);
        float s0 = sigmoidf_(c0[k]) * m;
        float s1 = sigmoidf_(c1[k]) * m;
        float w0 = m * s0, w1 = m * s1;
        acc[0] += s0; acc[7] += s1;
#pragma unroll
        for (int c = 0; c < 3; c++) {
            acc[1 + c]  += L[c][k]     * w0;
            acc[8 + c]  += L[3 + c][k] * w1;
            acc[4 + c]  += L[6 + c][k] * w0;
            acc[11 + c] += L[9 + c][k] * w1;
        }
    }
    __shared__ float red[4][14];
    int lane = tid & 63, wid = tid >> 6;
#pragma unroll
    for (int i = 0; i < 14; i++) {
        float v = acc[i];
        for (int off = 32; off > 0; off >>= 1) v += __shfl_down(v, off, 64);
        if (lane == 0) red[wid][i] = v;
    }
    __syncthreads();
    if (tid < 14)
        ws[512 + (b * NBLKV + bx) * 16 + tid] =
            red[0][tid] + red[1][tid] + red[2][tid] + red[3][tid];
}

// build M (redundant per block) + per-pixel minmax + copy ch {0,1,2,16..19}
__global__ __launch_bounds__(256) void k_minmax(const f4* __restrict__ in4,
                                                f4* __restrict__ out4,
                                                float* __restrict__ ws) {
    __shared__ float vsh[14];
    __shared__ float Msh[36];
    const int b = blockIdx.y, bx = blockIdx.x, tid = threadIdx.x;
    if (tid < 14) {
        const float* part = ws + 512 + (size_t)b * NBLKV * 16 + tid;
        float s = 0.f;
#pragma unroll 5
        for (int blk = 0; blk < NBLKV; blk++) s += part[blk * 16];
        vsh[tid] = s;
    }
    __syncthreads();
    if (tid < 3) {
        int k = tid;
        float lp0 = 0, lp1 = 0, lp2 = 0, rp0 = 0, rp1 = 0, rp2 = 0;
        if (k > 0) {
            const float* v = vsh + (k - 1) * 7;
            float d = v[0] + 1e-5f;
            lp0 = v[1] / d; lp1 = v[2] / d; lp2 = v[3] / d;
            rp0 = v[4] / d; rp1 = v[5] / d; rp2 = v[6] / d;
        }
        float rx = -rp0, ry = -rp1, rz = -rp2;
        float ang = sqrtf(rx * rx + ry * ry + rz * rz) + 1e-8f;
        float ax = rx / ang, ay = ry / ang, az = rz / ang;
        float K[3][3] = {{0.f, -az, ay}, {az, 0.f, -ax}, {-ay, ax, 0.f}};
        float c = cosf(ang), s = sinf(ang);
        float K2[3][3], Rm[3][3];
#pragma unroll
        for (int i = 0; i < 3; i++)
#pragma unroll
            for (int j = 0; j < 3; j++)
                K2[i][j] = K[i][0] * K[0][j] + K[i][1] * K[1][j] + K[i][2] * K[2][j];
#pragma unroll
        for (int i = 0; i < 3; i++)
#pragma unroll
            for (int j = 0; j < 3; j++)
                Rm[i][j] = (i == j ? 1.f : 0.f) + s * K[i][j] + (1.f - c) * K2[i][j];
#pragma unroll
        for (int i = 0; i < 3; i++) {
            float tt = (i == 0 ? lp0 : (i == 1 ? lp1 : lp2));
            float tr = tt - (Rm[i][0] * lp0 + Rm[i][1] * lp1 + Rm[i][2] * lp2);
            Msh[k * 12 + i * 4 + 0] = Rm[i][0];
            Msh[k * 12 + i * 4 + 1] = Rm[i][1];
            Msh[k * 12 + i * 4 + 2] = Rm[i][2];
            Msh[k * 12 + i * 4 + 3] = tr;
            if (bx == 0) {
                float* M = ws + 64 + (b * 3 + k) * 12;
                M[i * 4 + 0] = Rm[i][0]; M[i * 4 + 1] = Rm[i][1];
                M[i * 4 + 2] = Rm[i][2]; M[i * 4 + 3] = tr;
            }
        }
    }
    __syncthreads();

    const size_t ib = (size_t)b * NCH * HW4 + bx * 256 + tid;
    const size_t ob = (size_t)b * OCH * HW4 + bx * 256 + tid;
    f4 n0 = in4[ib], n1 = in4[ib + HW4], n2 = in4[ib + 2 * HW4];
    f4 mv = in4[ib + 3 * HW4];
    f4 g0 = in4[ib + 16 * HW4], g1 = in4[ib + 17 * HW4];
    f4 g2 = in4[ib + 18 * HW4], g3 = in4[ib + 19 * HW4];
    __builtin_nontemporal_store(n0, &out4[ob]);
    __builtin_nontemporal_store(n1, &out4[ob + HW4]);
    __builtin_nontemporal_store(n2, &out4[ob + 2 * HW4]);
    __builtin_nontemporal_store(g0, &out4[ob + 16 * HW4]);
    __builtin_nontemporal_store(g1, &out4[ob + 17 * HW4]);
    __builtin_nontemporal_store(g2, &out4[ob + 18 * HW4]);
    __builtin_nontemporal_store(g3, &out4[ob + 19 * HW4]);

    float mn[3] = {BIGF, BIGF, BIGF}, mx[3] = {-BIGF, -BIGF, -BIGF};
#pragma unroll
    for (int k = 0; k < 4; k++) {
        float m = sigmoidf_(mv[k]);
        if (!(m > THRESHF)) continue;
        int am = 0; float bb = g0[k];
        if (g1[k] > bb) { bb = g1[k]; am = 1; }
        if (g2[k] > bb) { bb = g2[k]; am = 2; }
        if (g3[k] > bb) { bb = g3[k]; am = 3; }
        float px = 0.f, py = 0.f, pz = 0.f;
        if (am > 0) {
            const float* Mk = Msh + (am - 1) * 12;
            float a = n0[k], bq = n1[k], cq = n2[k];
            px = Mk[0] * a + Mk[1] * bq + Mk[2]  * cq + Mk[3];
            py = Mk[4] * a + Mk[5] * bq + Mk[6]  * cq + Mk[7];
            pz = Mk[8] * a + Mk[9] * bq + Mk[10] * cq + Mk[11];
        }
        mn[0] = fminf(mn[0], px); mn[1] = fminf(mn[1], py); mn[2] = fminf(mn[2], pz);
        mx[0] = fmaxf(mx[0], px); mx[1] = fmaxf(mx[1], py); mx[2] = fmaxf(mx[2], pz);
    }
    __shared__ float rmn[4][3], rmx[4][3];
    int lane = tid & 63, wid = tid >> 6;
#pragma unroll
    for (int i = 0; i < 3; i++) {
        float v = mn[i];
        for (int off = 32; off > 0; off >>= 1) v = fminf(v, __shfl_down(v, off, 64));
        if (lane == 0) rmn[wid][i] = v;
        float u = mx[i];
        for (int off = 32; off > 0; off >>= 1) u = fmaxf(u, __shfl_down(u, off, 64));
        if (lane == 0) rmx[wid][i] = u;
    }
    __syncthreads();
    unsigned* keys = (unsigned*)(ws + 256);
    if (tid < 3) {
        float v = fminf(fminf(rmn[0][tid], rmn[1][tid]), fminf(rmn[2][tid], rmn[3][tid]));
        atomicMin(&keys[b * 6 + tid], fkey(v));
    } else if (tid < 6) {
        int i = tid - 3;
        float v = fmaxf(fmaxf(rmx[0][i], rmx[1][i]), fmaxf(rmx[2][i], rmx[3][i]));
        atomicMax(&keys[b * 6 + 3 + i], fkey(v));
    }
}

// feat copy (22..85) + pn (86..88) + dedup'd voxel scatter. 256 px/block.
template<bool VOXMAJOR>
__global__ __launch_bounds__(256) void k_scatter(const f4* __restrict__ in4,
                                                 f4* __restrict__ out4,
                                                 float* __restrict__ dst,
                                                 const float* __restrict__ ws) {
    __shared__ float tile[64][257];
    const int b = blockIdx.y, blk = blockIdx.x;
    const int tid = threadIdx.x, lane = tid & 63, w = tid >> 6;
    const size_t ib4 = (size_t)b * NCH * HW4 + blk * 64;
    const size_t ob4 = (size_t)b * OCH * HW4 + blk * 64;

    // prep decode (uniform per thread)
    const unsigned* keys = (const unsigned*)(ws + 256);
    float l0 = funkey(keys[b * 6 + 0]), l1 = funkey(keys[b * 6 + 1]), l2 = funkey(keys[b * 6 + 2]);
    float u0 = funkey(keys[b * 6 + 3]), u1 = funkey(keys[b * 6 + 4]), u2 = funkey(keys[b * 6 + 5]);
    float scale = fmaxf(u0 - l0, fmaxf(u1 - l1, u2 - l2));
    float safe = (scale == 0.f) ? 1.f : scale;
    bool flag = scale != 0.f;
    float z0 = flag ? (0.f - l0) / safe : 0.f;
    float z1 = flag ? (0.f - l1) / safe : 0.f;
    float z2 = flag ? (0.f - l2) / safe : 0.f;
    const int fl0 = vox1(z0) * 1024 + vox1(z1) * 32 + vox1(z2);

    // feat ch 22..85: NT copy + LDS stage (wave w: channels w*16..w*16+16)
#pragma unroll 4
    for (int i = 0; i < 16; i++) {
        int c = w * 16 + i;
        f4 v = __builtin_nontemporal_load(&in4[ib4 + (size_t)(22 + c) * HW4 + lane]);
        __builtin_nontemporal_store(v, &out4[ob4 + (size_t)(22 + c) * HW4 + lane]);
        tile[c][4 * lane + 0] = v[0]; tile[c][4 * lane + 1] = v[1];
        tile[c][4 * lane + 2] = v[2]; tile[c][4 * lane + 3] = v[3];
    }

    // per-pixel info (px = blk*256 + tid), scalar L2/L3-hot reads
    const float* ibs = (const float*)in4 + (size_t)b * NCH * HW + blk * 256 + tid;
    float* obs = (float*)out4 + (size_t)b * OCH * HW + blk * 256 + tid;
    float n0 = ibs[0], n1 = ibs[(size_t)HW], n2 = ibs[(size_t)2 * HW];
    float mvv = ibs[(size_t)3 * HW];
    float g0 = ibs[(size_t)16 * HW], g1 = ibs[(size_t)17 * HW];
    float g2 = ibs[(size_t)18 * HW], g3 = ibs[(size_t)19 * HW];
    float m = sigmoidf_(mvv);
    bool masked = m > THRESHF;
    int am = 0;
    { float bb = g0;
      if (g1 > bb) { bb = g1; am = 1; }
      if (g2 > bb) { bb = g2; am = 2; }
      if (g3 > bb) { bb = g3; am = 3; } }
    float px = 0.f, py = 0.f, pz = 0.f;
    if (am > 0) {
        const float* Mk = ws + 64 + b * 36 + (am - 1) * 12;
        px = Mk[0] * n0 + Mk[1] * n1 + Mk[2]  * n2 + Mk[3];
        py = Mk[4] * n0 + Mk[5] * n1 + Mk[6]  * n2 + Mk[7];
        pz = Mk[8] * n0 + Mk[9] * n1 + Mk[10] * n2 + Mk[11];
    }
    float qx, qy, qz;
    if (flag) { qx = (px - l0) / safe; qy = (py - l1) / safe; qz = (pz - l2) / safe; }
    else      { qx = px; qy = py; qz = pz; }
    float ox = masked ? qx : 0.f, oy = masked ? qy : 0.f, oz = masked ? qz : 0.f;
    __builtin_nontemporal_store(ox, &obs[(size_t)86 * HW]);
    __builtin_nontemporal_store(oy, &obs[(size_t)87 * HW]);
    __builtin_nontemporal_store(oz, &obs[(size_t)88 * HW]);
    // spec (am==0) pixels share voxel fl0 -> same dedup path
    int flat = masked ? ((am != 0) ? (vox1(ox) * 1024 + vox1(oy) * 32 + vox1(oz)) : fl0)
                      : -1;

    unsigned long long gm = __ballot(masked);
    __syncthreads();   // tile ready

    // dedup'd scatter: one 256B wave-atomic per DISTINCT voxel in the wave
    while (gm) {
        int i = __ffsll(gm) - 1;
        int fl = __shfl(flat, i, 64);
        unsigned long long match = __ballot(flat == fl) & gm;
        gm &= ~match;
        float s = 0.f;
        unsigned long long mm = match;
        while (mm) {
            int j = __ffsll(mm) - 1; mm &= mm - 1;
            s += tile[lane][w * 64 + j];
        }
        if (VOXMAJOR)
            atomicAdd(&dst[(((size_t)b * VOX + fl) << 6) + lane], s);
        else
            atomicAdd(&dst[(((size_t)(b * 64 + lane)) << 15) + fl], s);
    }
}

// tmp[b][vox][64] -> occ[b][64][vox]
__global__ __launch_bounds__(256) void k_transpose(const float* __restrict__ tmp,
                                                   float* __restrict__ occ) {
    __shared__ float ld[64][65];
    const int b = blockIdx.y;
    const int vox0 = blockIdx.x * 64;
    const int t = threadIdx.x;
    const int v = t & 63, g = t >> 6;
    const float* src = tmp + (((size_t)b * VOX + vox0 + v) << 6) + g * 16;
#pragma unroll
    for (int i = 0; i < 4; i++) {
        f4 x = *(const f4*)(src + 4 * i);
        ld[g * 16 + 4 * i + 0][v] = x[0];
        ld[g * 16 + 4 * i + 1][v] = x[1];
        ld[g * 16 + 4 * i + 2][v] = x[2];
        ld[g * 16 + 4 * i + 3][v] = x[3];
    }
    __syncthreads();
    const int f = t >> 2;
    float* dstp = occ + (((size_t)(b * 64 + f)) << 15) + vox0;
#pragma unroll
    for (int i = 0; i < 4; i++) {
        int mq = (t & 3) * 4 + i;
        f4 x;
        x[0] = ld[f][4 * mq + 0]; x[1] = ld[f][4 * mq + 1];
        x[2] = ld[f][4 * mq + 2]; x[3] = ld[f][4 * mq + 3];
        __builtin_nontemporal_store(x, (f4*)(dstp + 4 * mq));
    }
}

extern "C" void kernel_launch(void* const* d_in, const int* in_sizes, int n_in,
                              void* d_out, int out_size, void* d_ws, size_t ws_size,
                              hipStream_t stream) {
    const f4* in4 = (const f4*)d_in[0];
    float* out = (float*)d_out;
    float* ws = (float*)d_ws;
    float* occ = out + (size_t)NB * OCH * HW;
    float* tmp = ws + 32768;
    const size_t tmp_bytes = (size_t)NB * VOX * 64 * sizeof(float);
    const bool voxmajor = ws_size >= 32768 * sizeof(float) + tmp_bytes;
    const unsigned n4 = (unsigned)(tmp_bytes / 16);

    dim3 g75(NBLKV, NB);
    if (voxmajor) k_votes_zero<<<g75, 256, 0, stream>>>(in4, (f4*)out, ws, (f4*)tmp, n4);
    else          k_votes_zero<<<g75, 256, 0, stream>>>(in4, (f4*)out, ws, (f4*)occ, n4);
    k_minmax<<<g75, 256, 0, stream>>>(in4, (f4*)out, ws);
    dim3 gs(300, NB);
    if (voxmajor) {
        k_scatter<true><<<gs, 256, 0, stream>>>(in4, (f4*)out, tmp, ws);
        dim3 gt(VOX / 64, NB);
        k_transpose<<<gt, 256, 0, stream>>>(tmp, occ);
    } else {
        k_scatter<false><<<gs, 256, 0, stream>>>(in4, (f4*)out, occ, ws);
    }
}

// Round 8
// 157.399 us; speedup vs baseline: 1.1310x; 1.1310x over previous
//
#include <hip/hip_runtime.h>
#include <math.h>

#define HW     76800
#define HW4    19200
#define NCH    86
#define OCH    89
#define NB     4
#define VOX    32768
#define NBLKV  75         // f4 blocks per batch (1024 px each)
#define THRESHF 0.7f
#define BIGF   1e30f

typedef float f4 __attribute__((ext_vector_type(4)));

// ws float layout:
// [64..207]   M: (b*3 + k)*12 row-major 3x4 [R|t]     (written by k_minmax bx==0)
// [256..279]  minmax keys (uint32): b*6 + c           (init by k_votes_zero blk(0,0))
// [512..5312) vote partials: (b*75+bx)*16 + i, i<14   (k_votes_zero)
// [32768..]   occ_tmp: [b][vox][64] voxel-major scratch (33.5 MB)

__device__ __forceinline__ float sigmoidf_(float x) {
    if (x >= 0.f) { return 1.f / (1.f + expf(-x)); }
    float e = expf(x); return e / (1.f + e);
}
__device__ __forceinline__ unsigned fkey(float f) {
    unsigned u = __float_as_uint(f);
    return (u & 0x80000000u) ? ~u : (u | 0x80000000u);
}
__device__ __forceinline__ float funkey(unsigned k) {
    unsigned u = (k & 0x80000000u) ? (k ^ 0x80000000u) : ~k;
    return __uint_as_float(u);
}
__device__ __forceinline__ int vox1(float q) {
    int v = (int)floorf(q * 32.f);
    return v < 0 ? 0 : (v > 31 ? 31 : v);
}

// votes (f4, per-block partials) + zero occ_tmp + init minmax keys. NO copies
// (copies in low-parallelism kernels regressed 35 µs in R7).
__global__ __launch_bounds__(256) void k_votes_zero(const f4* __restrict__ in4,
                                                    float* __restrict__ ws,
                                                    f4* __restrict__ zp, unsigned n4) {
    const int b = blockIdx.y, bx = blockIdx.x;
    const int tid = threadIdx.x;
    {   // zero slice of scratch
        unsigned gid = ((unsigned)(b * NBLKV + bx)) * 256u + tid;
        f4 z = {0.f, 0.f, 0.f, 0.f};
        for (unsigned i = gid; i < n4; i += NB * NBLKV * 256u)
            __builtin_nontemporal_store(z, &zp[i]);
    }
    if (b == 0 && bx == 0 && tid < 24) {
        unsigned* keys = (unsigned*)(ws + 256);
        keys[tid] = ((tid % 6) < 3) ? fkey(BIGF) : fkey(-BIGF);
    }
    const size_t ib = (size_t)b * NCH * HW4 + bx * 256 + tid;
    f4 mv = in4[ib + (size_t)3 * HW4];
    f4 c0 = in4[ib + (size_t)20 * HW4];
    f4 c1 = in4[ib + (size_t)21 * HW4];
    f4 L[12];
#pragma unroll
    for (int i = 0; i < 12; i++) L[i] = in4[ib + (size_t)(4 + i) * HW4];
    float acc[14];
#pragma unroll
    for (int i = 0; i < 14; i++) acc[i] = 0.f;
#pragma unroll
    for (int k = 0; k < 4; k++) {
        float m  = sigmoidf_(mv[k]);
        float s0 = sigmoidf_(c0[k]) * m;
        float s1 = sigmoidf_(c1[k]) * m;
        float w0 = m * s0, w1 = m * s1;
        acc[0] += s0; acc[7] += s1;
#pragma unroll
        for (int c = 0; c < 3; c++) {
            acc[1 + c]  += L[c][k]     * w0;
            acc[8 + c]  += L[3 + c][k] * w1;
            acc[4 + c]  += L[6 + c][k] * w0;
            acc[11 + c] += L[9 + c][k] * w1;
        }
    }
    __shared__ float red[4][14];
    int lane = tid & 63, wid = tid >> 6;
#pragma unroll
    for (int i = 0; i < 14; i++) {
        float v = acc[i];
        for (int off = 32; off > 0; off >>= 1) v += __shfl_down(v, off, 64);
        if (lane == 0) red[wid][i] = v;
    }
    __syncthreads();
    if (tid < 14)
        ws[512 + (b * NBLKV + bx) * 16 + tid] =
            red[0][tid] + red[1][tid] + red[2][tid] + red[3][tid];
}

// build M (redundant per block, from partials) + per-pixel minmax (f4). NO copies.
__global__ __launch_bounds__(256) void k_minmax(const f4* __restrict__ in4,
                                                float* __restrict__ ws) {
    __shared__ float vsh[14];
    __shared__ float Msh[36];
    const int b = blockIdx.y, bx = blockIdx.x, tid = threadIdx.x;
    if (tid < 14) {
        const float* part = ws + 512 + (size_t)b * NBLKV * 16 + tid;
        float s = 0.f;
#pragma unroll 5
        for (int blk = 0; blk < NBLKV; blk++) s += part[blk * 16];
        vsh[tid] = s;
    }
    __syncthreads();
    if (tid < 3) {
        int k = tid;
        float lp0 = 0, lp1 = 0, lp2 = 0, rp0 = 0, rp1 = 0, rp2 = 0;
        if (k > 0) {
            const float* v = vsh + (k - 1) * 7;
            float d = v[0] + 1e-5f;
            lp0 = v[1] / d; lp1 = v[2] / d; lp2 = v[3] / d;
            rp0 = v[4] / d; rp1 = v[5] / d; rp2 = v[6] / d;
        }
        float rx = -rp0, ry = -rp1, rz = -rp2;
        float ang = sqrtf(rx * rx + ry * ry + rz * rz) + 1e-8f;
        float ax = rx / ang, ay = ry / ang, az = rz / ang;
        float K[3][3] = {{0.f, -az, ay}, {az, 0.f, -ax}, {-ay, ax, 0.f}};
        float c = cosf(ang), s = sinf(ang);
        float K2[3][3], Rm[3][3];
#pragma unroll
        for (int i = 0; i < 3; i++)
#pragma unroll
            for (int j = 0; j < 3; j++)
                K2[i][j] = K[i][0] * K[0][j] + K[i][1] * K[1][j] + K[i][2] * K[2][j];
#pragma unroll
        for (int i = 0; i < 3; i++)
#pragma unroll
            for (int j = 0; j < 3; j++)
                Rm[i][j] = (i == j ? 1.f : 0.f) + s * K[i][j] + (1.f - c) * K2[i][j];
#pragma unroll
        for (int i = 0; i < 3; i++) {
            float tt = (i == 0 ? lp0 : (i == 1 ? lp1 : lp2));
            float tr = tt - (Rm[i][0] * lp0 + Rm[i][1] * lp1 + Rm[i][2] * lp2);
            Msh[k * 12 + i * 4 + 0] = Rm[i][0];
            Msh[k * 12 + i * 4 + 1] = Rm[i][1];
            Msh[k * 12 + i * 4 + 2] = Rm[i][2];
            Msh[k * 12 + i * 4 + 3] = tr;
            if (bx == 0) {
                float* M = ws + 64 + (b * 3 + k) * 12;
                M[i * 4 + 0] = Rm[i][0]; M[i * 4 + 1] = Rm[i][1];
                M[i * 4 + 2] = Rm[i][2]; M[i * 4 + 3] = tr;
            }
        }
    }
    __syncthreads();

    const size_t ib = (size_t)b * NCH * HW4 + bx * 256 + tid;
    f4 n0 = in4[ib], n1 = in4[ib + HW4], n2 = in4[ib + 2 * HW4];
    f4 mv = in4[ib + 3 * HW4];
    f4 g0 = in4[ib + 16 * HW4], g1 = in4[ib + 17 * HW4];
    f4 g2 = in4[ib + 18 * HW4], g3 = in4[ib + 19 * HW4];
    float mn[3] = {BIGF, BIGF, BIGF}, mx[3] = {-BIGF, -BIGF, -BIGF};
#pragma unroll
    for (int k = 0; k < 4; k++) {
        float m = sigmoidf_(mv[k]);
        if (!(m > THRESHF)) continue;
        int am = 0; float bb = g0[k];
        if (g1[k] > bb) { bb = g1[k]; am = 1; }
        if (g2[k] > bb) { bb = g2[k]; am = 2; }
        if (g3[k] > bb) { bb = g3[k]; am = 3; }
        float px = 0.f, py = 0.f, pz = 0.f;
        if (am > 0) {
            const float* Mk = Msh + (am - 1) * 12;
            float a = n0[k], bq = n1[k], cq = n2[k];
            px = Mk[0] * a + Mk[1] * bq + Mk[2]  * cq + Mk[3];
            py = Mk[4] * a + Mk[5] * bq + Mk[6]  * cq + Mk[7];
            pz = Mk[8] * a + Mk[9] * bq + Mk[10] * cq + Mk[11];
        }
        mn[0] = fminf(mn[0], px); mn[1] = fminf(mn[1], py); mn[2] = fminf(mn[2], pz);
        mx[0] = fmaxf(mx[0], px); mx[1] = fmaxf(mx[1], py); mx[2] = fmaxf(mx[2], pz);
    }
    __shared__ float rmn[4][3], rmx[4][3];
    int lane = tid & 63, wid = tid >> 6;
#pragma unroll
    for (int i = 0; i < 3; i++) {
        float v = mn[i];
        for (int off = 32; off > 0; off >>= 1) v = fminf(v, __shfl_down(v, off, 64));
        if (lane == 0) rmn[wid][i] = v;
        float u = mx[i];
        for (int off = 32; off > 0; off >>= 1) u = fmaxf(u, __shfl_down(u, off, 64));
        if (lane == 0) rmx[wid][i] = u;
    }
    __syncthreads();
    unsigned* keys = (unsigned*)(ws + 256);
    if (tid < 3) {
        float v = fminf(fminf(rmn[0][tid], rmn[1][tid]), fminf(rmn[2][tid], rmn[3][tid]));
        atomicMin(&keys[b * 6 + tid], fkey(v));
    } else if (tid < 6) {
        int i = tid - 3;
        float v = fmaxf(fmaxf(rmx[0][i], rmx[1][i]), fmaxf(rmx[2][i], rmx[3][i]));
        atomicMax(&keys[b * 6 + 3 + i], fkey(v));
    }
}

// ALL out_cat copies + pn + dedup'd voxel scatter, 256 px/block.
// Feat channels in 2 passes of 32 -> LDS 33 KB -> 4 blocks/CU (was 2 at 66 KB).
// Drain: 2 distinct voxels/iteration (lane = half*32 + ch), 128B atomics.
template<bool VOXMAJOR>
__global__ __launch_bounds__(256) void k_scatter(const f4* __restrict__ in4,
                                                 f4* __restrict__ out4,
                                                 float* __restrict__ dst,
                                                 const float* __restrict__ ws) {
    __shared__ float tile[32][257];
    const int b = blockIdx.y, blk = blockIdx.x;
    const int tid = threadIdx.x, lane = tid & 63, w = tid >> 6;
    const size_t ib4 = (size_t)b * NCH * HW4 + (size_t)blk * 64;
    const size_t ob4 = (size_t)b * OCH * HW4 + (size_t)blk * 64;

    // prep decode (uniform per thread)
    const unsigned* keys = (const unsigned*)(ws + 256);
    float l0 = funkey(keys[b * 6 + 0]), l1 = funkey(keys[b * 6 + 1]), l2 = funkey(keys[b * 6 + 2]);
    float u0 = funkey(keys[b * 6 + 3]), u1 = funkey(keys[b * 6 + 4]), u2 = funkey(keys[b * 6 + 5]);
    float scale = fmaxf(u0 - l0, fmaxf(u1 - l1, u2 - l2));
    float safe = (scale == 0.f) ? 1.f : scale;
    bool flag = scale != 0.f;
    float z0 = flag ? (0.f - l0) / safe : 0.f;
    float z1 = flag ? (0.f - l1) / safe : 0.f;
    float z2 = flag ? (0.f - l2) / safe : 0.f;
    const int fl0 = vox1(z0) * 1024 + vox1(z1) * 32 + vox1(z2);

    // phase A: copy ch 0..21 (regular loads -> L1/L2-hot for phase B)
    for (int c = w; c < 22; c += 4) {
        f4 v = in4[ib4 + (size_t)c * HW4 + lane];
        __builtin_nontemporal_store(v, &out4[ob4 + (size_t)c * HW4 + lane]);
    }

    // phase B: per-pixel info (px = blk*256 + tid), scalar L1-hot reads
    const float* ibs = (const float*)in4 + (size_t)b * NCH * HW + blk * 256 + tid;
    float* obs = (float*)out4 + (size_t)b * OCH * HW + blk * 256 + tid;
    float n0 = ibs[0], n1 = ibs[(size_t)HW], n2 = ibs[(size_t)2 * HW];
    float mvv = ibs[(size_t)3 * HW];
    float g0 = ibs[(size_t)16 * HW], g1 = ibs[(size_t)17 * HW];
    float g2 = ibs[(size_t)18 * HW], g3 = ibs[(size_t)19 * HW];
    float m = sigmoidf_(mvv);
    bool masked = m > THRESHF;
    int am = 0;
    { float bb = g0;
      if (g1 > bb) { bb = g1; am = 1; }
      if (g2 > bb) { bb = g2; am = 2; }
      if (g3 > bb) { bb = g3; am = 3; } }
    float px = 0.f, py = 0.f, pz = 0.f;
    if (am > 0) {
        const float* Mk = ws + 64 + b * 36 + (am - 1) * 12;
        px = Mk[0] * n0 + Mk[1] * n1 + Mk[2]  * n2 + Mk[3];
        py = Mk[4] * n0 + Mk[5] * n1 + Mk[6]  * n2 + Mk[7];
        pz = Mk[8] * n0 + Mk[9] * n1 + Mk[10] * n2 + Mk[11];
    }
    float qx, qy, qz;
    if (flag) { qx = (px - l0) / safe; qy = (py - l1) / safe; qz = (pz - l2) / safe; }
    else      { qx = px; qy = py; qz = pz; }
    float ox = masked ? qx : 0.f, oy = masked ? qy : 0.f, oz = masked ? qz : 0.f;
    __builtin_nontemporal_store(ox, &obs[(size_t)86 * HW]);
    __builtin_nontemporal_store(oy, &obs[(size_t)87 * HW]);
    __builtin_nontemporal_store(oz, &obs[(size_t)88 * HW]);
    int flat = masked ? ((am != 0) ? (vox1(ox) * 1024 + vox1(oy) * 32 + vox1(oz)) : fl0)
                      : -1;

    const unsigned long long gm_all = __ballot(masked);
    const int ch = lane & 31, half = lane >> 5;

#pragma unroll
    for (int p = 0; p < 2; p++) {
        if (p) __syncthreads();   // previous drain must finish before restaging
        // stage: wave w -> channels w*8 .. w*8+7 (within pass) + NT copy out
#pragma unroll
        for (int i = 0; i < 8; i++) {
            int c = w * 8 + i;                    // 0..31
            int cg = 22 + p * 32 + c;
            f4 v = __builtin_nontemporal_load(&in4[ib4 + (size_t)cg * HW4 + lane]);
            __builtin_nontemporal_store(v, &out4[ob4 + (size_t)cg * HW4 + lane]);
            tile[c][4 * lane + 0] = v[0]; tile[c][4 * lane + 1] = v[1];
            tile[c][4 * lane + 2] = v[2]; tile[c][4 * lane + 3] = v[3];
        }
        __syncthreads();          // tile ready
        // drain: 2 distinct voxels per iteration
        unsigned long long gm = gm_all;
        while (gm) {
            int i0 = __ffsll(gm) - 1;
            int f0 = __shfl(flat, i0, 64);
            unsigned long long m0 = __ballot(flat == f0) & gm;
            gm &= ~m0;
            int f1 = 0; unsigned long long m1 = 0;
            if (gm) {
                int i1 = __ffsll(gm) - 1;
                f1 = __shfl(flat, i1, 64);
                m1 = __ballot(flat == f1) & gm;
                gm &= ~m1;
            }
            unsigned long long mm = half ? m1 : m0;
            int fl = half ? f1 : f0;
            float s = 0.f;
            while (mm) {
                int j = __ffsll(mm) - 1; mm &= mm - 1;
                s += tile[ch][w * 64 + j];
            }
            if (!half || m1) {
                if (VOXMAJOR)
                    atomicAdd(&dst[(((size_t)b * VOX + fl) << 6) + p * 32 + ch], s);
                else
                    atomicAdd(&dst[(((size_t)(b * 64 + p * 32 + ch)) << 15) + fl], s);
            }
        }
    }
}

// tmp[b][vox][64] -> occ[b][64][vox]
__global__ __launch_bounds__(256) void k_transpose(const float* __restrict__ tmp,
                                                   float* __restrict__ occ) {
    __shared__ float ld[64][65];
    const int b = blockIdx.y;
    const int vox0 = blockIdx.x * 64;
    const int t = threadIdx.x;
    const int v = t & 63, g = t >> 6;
    const float* src = tmp + (((size_t)b * VOX + vox0 + v) << 6) + g * 16;
#pragma unroll
    for (int i = 0; i < 4; i++) {
        f4 x = *(const f4*)(src + 4 * i);
        ld[g * 16 + 4 * i + 0][v] = x[0];
        ld[g * 16 + 4 * i + 1][v] = x[1];
        ld[g * 16 + 4 * i + 2][v] = x[2];
        ld[g * 16 + 4 * i + 3][v] = x[3];
    }
    __syncthreads();
    const int f = t >> 2;
    float* dstp = occ + (((size_t)(b * 64 + f)) << 15) + vox0;
#pragma unroll
    for (int i = 0; i < 4; i++) {
        int mq = (t & 3) * 4 + i;
        f4 x;
        x[0] = ld[f][4 * mq + 0]; x[1] = ld[f][4 * mq + 1];
        x[2] = ld[f][4 * mq + 2]; x[3] = ld[f][4 * mq + 3];
        __builtin_nontemporal_store(x, (f4*)(dstp + 4 * mq));
    }
}

extern "C" void kernel_launch(void* const* d_in, const int* in_sizes, int n_in,
                              void* d_out, int out_size, void* d_ws, size_t ws_size,
                              hipStream_t stream) {
    const f4* in4 = (const f4*)d_in[0];
    float* out = (float*)d_out;
    float* ws = (float*)d_ws;
    float* occ = out + (size_t)NB * OCH * HW;
    float* tmp = ws + 32768;
    const size_t tmp_bytes = (size_t)NB * VOX * 64 * sizeof(float);
    const bool voxmajor = ws_size >= 32768 * sizeof(float) + tmp_bytes;
    const unsigned n4 = (unsigned)(tmp_bytes / 16);

    dim3 g75(NBLKV, NB);
    if (voxmajor) k_votes_zero<<<g75, 256, 0, stream>>>(in4, ws, (f4*)tmp, n4);
    else          k_votes_zero<<<g75, 256, 0, stream>>>(in4, ws, (f4*)occ, n4);
    k_minmax<<<g75, 256, 0, stream>>>(in4, ws);
    dim3 gs(300, NB);
    if (voxmajor) {
        k_scatter<true><<<gs, 256, 0, stream>>>(in4, (f4*)out, tmp, ws);
        dim3 gt(VOX / 64, NB);
        k_transpose<<<gt, 256, 0, stream>>>(tmp, occ);
    } else {
        k_scatter<false><<<gs, 256, 0, stream>>>(in4, (f4*)out, occ, ws);
    }
}